// Round 1
// baseline (647.632 us; speedup 1.0000x reference)
//
#include <hip/hip_runtime.h>

// Problem constants (from reference setup)
constexpr int N_ = 2, Z_ = 40, Y_ = 400, X_ = 400;
constexpr int G_ = 30000;     // grid query positions
constexpr int M_ = 120000;    // feature rows
constexpr int C_ = 64;        // channels
constexpr int K_ = 64;        // neighborhood size (p=4 -> 4^3)

// Output layout (flat, in return order):
//   sampled_features: [C, G, K]  = C_*G_*K_ floats
//   gpf:              [4, G, K]  = 4*G_*K_ floats
//   empty_mask:       [G]        = G_ floats (bool -> 0.0/1.0)

__global__ __launch_bounds__(256) void grouper_kernel(
    const int*   __restrict__ voxel_maps,     // [N,Z,Y,X]
    const int*   __restrict__ grid_positions, // [G,4]
    const float* __restrict__ features,       // [M,C]
    const int*   __restrict__ index_offset,   // [1,K,4]
    float*       __restrict__ out)
{
    const int wave = threadIdx.x >> 6;   // 4 waves/block, one g per wave
    const int lane = threadIdx.x & 63;   // lane == k  (K == wavefront size)
    const int g = blockIdx.x * 4 + wave;
    if (g >= G_) return;
    const int k = lane;

    const long long GK = (long long)G_ * K_;

    // per-k offset [dn, d1, d2, d3]; int4 load is 16B-aligned & coalesced
    const int4 off = ((const int4*)index_offset)[k];
    // wave-uniform grid position
    const int4 gp  = ((const int4*)grid_positions)[g];

    const int n = gp.x + off.x;                        // off.x == 0, no clip in ref
    const int z = min(max(gp.y + off.y, 0), Z_ - 1);
    const int y = min(max(gp.z + off.z, 0), Y_ - 1);
    const int x = min(max(gp.w + off.w, 0), X_ - 1);

    const int sidx = voxel_maps[((n * Z_ + z) * Y_ + y) * X_ + x];

    float* out_sf   = out;                              // [C,G,K]
    float* out_gpf  = out + (long long)C_ * GK;         // [4,G,K]
    float* out_mask = out + (long long)(C_ + 4) * GK;   // [G]

    const long long gk = (long long)g * K_ + k;

    // gpf: integer positions contribute 0 after (x - floor(x)); only raw offsets remain
    out_gpf[0 * GK + gk] = (float)off.x;
    out_gpf[1 * GK + gk] = (float)off.y;
    out_gpf[2 * GK + gk] = (float)off.z;
    out_gpf[3 * GK + gk] = (float)off.w;

    // empty mask: sum_k (sidx+1) == 0  <=>  all sidx == -1 (each term >= 0)
    const bool all_empty = __all(sidx == -1);
    if (lane == 0) out_mask[g] = all_empty ? 1.0f : 0.0f;

    // sampled features: row gather (256B contiguous per lane), writes coalesced
    // across the wave (64 lanes x 4B contiguous per channel c)
    if (sidx < 0) {
        #pragma unroll
        for (int c = 0; c < C_; ++c)
            out_sf[(long long)c * GK + gk] = 0.0f;
    } else {
        const float4* frow = (const float4*)(features + (long long)sidx * C_);
        #pragma unroll
        for (int q = 0; q < C_ / 4; ++q) {
            const float4 v = frow[q];
            out_sf[(long long)(4 * q + 0) * GK + gk] = v.x;
            out_sf[(long long)(4 * q + 1) * GK + gk] = v.y;
            out_sf[(long long)(4 * q + 2) * GK + gk] = v.z;
            out_sf[(long long)(4 * q + 3) * GK + gk] = v.w;
        }
    }
}

extern "C" void kernel_launch(void* const* d_in, const int* in_sizes, int n_in,
                              void* d_out, int out_size, void* d_ws, size_t ws_size,
                              hipStream_t stream) {
    const int*   voxel_maps     = (const int*)d_in[0];
    const int*   grid_positions = (const int*)d_in[1];
    const float* features       = (const float*)d_in[2];
    const int*   index_offset   = (const int*)d_in[3];
    float*       out            = (float*)d_out;

    const int waves_per_block = 4;                      // 256 threads
    const int blocks = (G_ + waves_per_block - 1) / waves_per_block;  // 7500
    grouper_kernel<<<blocks, 256, 0, stream>>>(
        voxel_maps, grid_positions, features, index_offset, out);
}